// Round 9
// baseline (573.654 us; speedup 1.0000x reference)
//
#include <hip/hip_runtime.h>

typedef unsigned short ushort_t;
typedef unsigned int uint_t;
typedef short short8 __attribute__((ext_vector_type(8)));
typedef float f32x4 __attribute__((ext_vector_type(4)));
typedef float f32x2 __attribute__((ext_vector_type(2)));
typedef uint_t u32x2 __attribute__((ext_vector_type(2)));
typedef _Float16 half2_t __attribute__((ext_vector_type(2)));

__device__ __forceinline__ float sigm(float x) { return 1.f / (1.f + __expf(-x)); }
__device__ __forceinline__ float tanh_s(float x) {
  float e = __expf(2.f * fabsf(x));
  float r = 1.f - 2.f / (e + 1.f);
  return copysignf(r, x);
}
__device__ __forceinline__ float dot2h(half2_t a, half2_t b, float c) {
#if __has_builtin(__builtin_amdgcn_fdot2)
  return __builtin_amdgcn_fdot2(a, b, c, false);
#else
  return c + (float)a.x * (float)b.x + (float)a.y * (float)b.y;
#endif
}
__device__ __forceinline__ uint_t cvtpk_bf16(float a, float b) {
  uint_t r;
  asm("v_cvt_pk_bf16_f32 %0, %1, %2" : "=v"(r) : "v"(a), "v"(b));
  return r;
}
__device__ __forceinline__ short8 ld_cvt8(const float* p) {
  f32x4 v0 = *(const f32x4*)p;
  f32x4 v1 = *(const f32x4*)(p + 4);
  union { short8 s; uint_t u[4]; } r;
  r.u[0] = cvtpk_bf16(v0[0], v0[1]);
  r.u[1] = cvtpk_bf16(v0[2], v0[3]);
  r.u[2] = cvtpk_bf16(v1[0], v1[1]);
  r.u[3] = cvtpk_bf16(v1[2], v1[3]);
  return r.s;
}
__device__ __forceinline__ float f16b2f(uint_t bits) {
  union { ushort_t s; _Float16 h; } v; v.s = (ushort_t)bits; return (float)v.h;
}
__device__ __forceinline__ uint_t f2f16b(float f) {
  union { _Float16 h; ushort_t s; } v; v.h = (_Float16)f; return v.s;
}

#define MFMAB(a, b, c) __builtin_amdgcn_mfma_f32_16x16x32_bf16((a), (b), (c), 0, 0, 0)

// =====================================================================
// Kernel 1 (unchanged, measured ~70 us, PASS): fully-fused gate GEMM.
// G cell (8 bytes, u32x2): lo = {f16 g0+b0, f16 g3+b3}
//                          hi = {f16 g4+b4+gt2, u8 T1, u8 T2}
// =====================================================================
__global__ __launch_bounds__(512) void gemm_g(
    const float* __restrict__ x, const float* __restrict__ td,
    const float* __restrict__ wx, const float* __restrict__ wt,
    const float* __restrict__ bias, u32x2* __restrict__ G,
    int t0, int TC, int ltc, int rpt)
{
  const int tid = threadIdx.x;
  const int wv = tid >> 6, lane = tid & 63;
  const int l15 = lane & 15, lg = lane >> 4;
  const int jj = wv * 16 + l15;

  short8 Bx[5][2], Bt[3][2];
#pragma unroll
  for (int s = 0; s < 5; ++s)
#pragma unroll
    for (int f = 0; f < 2; ++f) {
      const float* wp = wx + (size_t)(f * 32 + lg * 8) * 640 + s * 128 + jj;
      union { short8 v; uint_t u[4]; } r;
#pragma unroll
      for (int q = 0; q < 4; ++q)
        r.u[q] = cvtpk_bf16(wp[(2 * q) * 640], wp[(2 * q + 1) * 640]);
      Bx[s][f] = r.v;
    }
#pragma unroll
  for (int s = 0; s < 3; ++s)
#pragma unroll
    for (int f = 0; f < 2; ++f) {
      const float* wp = wt + (size_t)(f * 32 + lg * 8) * 384 + s * 128 + jj;
      union { short8 v; uint_t u[4]; } r;
#pragma unroll
      for (int q = 0; q < 4; ++q) {
        float w0 = wp[(2 * q) * 384], w1 = wp[(2 * q + 1) * 384];
        if (s == 0) { w0 = fminf(w0, 0.f); w1 = fminf(w1, 0.f); }
        r.u[q] = cvtpk_bf16(w0, w1);
      }
      Bt[s][f] = r.v;
    }

  const float b0f = bias[jj], b1f = bias[128 + jj], b2f = bias[256 + jj];
  const float b3f = bias[384 + jj], b4f = bias[512 + jj];

#pragma unroll 1
  for (int it = 0; it < rpt; ++it) {
    const int m0 = (blockIdx.x * rpt + it) * 16;
    const int m = m0 + l15;
    const int bb = m >> ltc, tt = m & (TC - 1);
    const size_t ro = ((size_t)(bb * 512) + t0 + tt) * 64 + lg * 8;
    short8 xa0 = ld_cvt8(x + ro), xa1 = ld_cvt8(x + ro + 32);
    short8 ta0 = ld_cvt8(td + ro), ta1 = ld_cvt8(td + ro + 32);

    f32x4 g0{}, g1{}, g2{}, g3{}, g4{}, q0{}, q1{}, q2{};
    g0 = MFMAB(xa0, Bx[0][0], g0); g0 = MFMAB(xa1, Bx[0][1], g0);
    g1 = MFMAB(xa0, Bx[1][0], g1); g1 = MFMAB(xa1, Bx[1][1], g1);
    g2 = MFMAB(xa0, Bx[2][0], g2); g2 = MFMAB(xa1, Bx[2][1], g2);
    g3 = MFMAB(xa0, Bx[3][0], g3); g3 = MFMAB(xa1, Bx[3][1], g3);
    g4 = MFMAB(xa0, Bx[4][0], g4); g4 = MFMAB(xa1, Bx[4][1], g4);
    q0 = MFMAB(ta0, Bt[0][0], q0); q0 = MFMAB(ta1, Bt[0][1], q0);
    q1 = MFMAB(ta0, Bt[1][0], q1); q1 = MFMAB(ta1, Bt[1][1], q1);
    q2 = MFMAB(ta0, Bt[2][0], q2); q2 = MFMAB(ta1, Bt[2][1], q2);

#pragma unroll
    for (int r = 0; r < 4; ++r) {
      float v0 = g0[r] + b0f;
      float T1 = sigm(g1[r] + b1f + tanh_s(q0[r]));
      float T2 = sigm(g2[r] + b2f + tanh_s(q1[r]));
      float v3 = g3[r] + b3f;
      float v4 = g4[r] + b4f + q2[r];
      uint_t t1u = (uint_t)(T1 * 255.f + 0.5f);
      uint_t t2u = (uint_t)(T2 * 255.f + 0.5f);
      u32x2 P;
      P[0] = f2f16b(v0) | (f2f16b(v3) << 16);
      P[1] = f2f16b(v4) | (t1u << 16) | (t2u << 24);
      G[(size_t)(m0 + lg * 4 + r) * 128 + jj] = P;
    }
  }
}

// =====================================================================
// Kernel 2: serial scan, segment-collapsed.
// 1 block = 1 batch row, 128 threads (2 waves).  Thread j owns gate
// column j COMPLETELY: Wh cols {j, 128+j, 256+j} as 192 half2 in VGPRs,
// full k=128 dot (192 dot2, 12 chains) + gates in-lane.  xh never
// leaves registers.  h broadcast via 256B double-buffered LDS.
// ONE barrier per step.  G prefetched depth-4 in registers.
// =====================================================================
__global__ __launch_bounds__(128, 1) void scan_k(
    const u32x2* __restrict__ G, const float* __restrict__ wh,
    float* __restrict__ out, float* __restrict__ sh, float* __restrict__ sc,
    int t0, int t1, int TC)
{
  __shared__ __attribute__((aligned(16))) _Float16 h_lds[2][128];
  const int j = threadIdx.x;   // gate column 0..127
  const int b = blockIdx.x;

  // Wh columns {j, 128+j, 256+j} over k=0..127 as f16 pairs (192 VGPRs)
  half2_t w2[3][64];
#pragma unroll
  for (int s = 0; s < 3; ++s) {
    const float* wp = wh + s * 128 + j;
#pragma unroll
    for (int k = 0; k < 64; ++k)
      w2[s][k] = half2_t{(_Float16)wp[(size_t)(2 * k) * 384],
                         (_Float16)wp[(size_t)(2 * k + 1) * 384]};
  }

  float c_last = 0.f, h0v = 0.f;
  if (t0 > 0) { h0v = sh[b * 128 + j]; c_last = sc[b * 128 + j]; }
  float h_last = h0v;
  h_lds[0][j] = (_Float16)h0v;

  const u32x2* Gp = G + (size_t)b * TC * 128 + j;
  float* outp = out + (size_t)b * 65536 + j;

  u32x2 p0 = Gp[0], p1 = Gp[128], p2 = Gp[256], p3 = Gp[384];
  __syncthreads();

#define SCAN_STEP(P, TT, CUR, NXT)                                           \
  {                                                                          \
    u32x2 cur = P;                                                           \
    int tp = (TT) + 4; if (tp > TC - 1) tp = TC - 1;                         \
    P = Gp[(size_t)tp * 128];                                                \
    float a0=0.f,a1=0.f,a2=0.f,a3=0.f;                                       \
    float d0=0.f,d1=0.f,d2=0.f,d3=0.f;                                       \
    float e0=0.f,e1=0.f,e2=0.f,e3=0.f;                                       \
    const short8* hv8 = (const short8*)h_lds[CUR];                           \
    _Pragma("unroll")                                                        \
    for (int kk = 0; kk < 16; ++kk) {                                        \
      union { short8 s; half2_t h[4]; } u; u.s = hv8[kk];                    \
      a0 = dot2h(u.h[0], w2[0][kk * 4 + 0], a0);                             \
      a1 = dot2h(u.h[1], w2[0][kk * 4 + 1], a1);                             \
      a2 = dot2h(u.h[2], w2[0][kk * 4 + 2], a2);                             \
      a3 = dot2h(u.h[3], w2[0][kk * 4 + 3], a3);                             \
      d0 = dot2h(u.h[0], w2[1][kk * 4 + 0], d0);                             \
      d1 = dot2h(u.h[1], w2[1][kk * 4 + 1], d1);                             \
      d2 = dot2h(u.h[2], w2[1][kk * 4 + 2], d2);                             \
      d3 = dot2h(u.h[3], w2[1][kk * 4 + 3], d3);                             \
      e0 = dot2h(u.h[0], w2[2][kk * 4 + 0], e0);                             \
      e1 = dot2h(u.h[1], w2[2][kk * 4 + 1], e1);                             \
      e2 = dot2h(u.h[2], w2[2][kk * 4 + 2], e2);                             \
      e3 = dot2h(u.h[3], w2[2][kk * 4 + 3], e3);                             \
    }                                                                        \
    float xh0 = (a0 + a1) + (a2 + a3);                                       \
    float xh1 = (d0 + d1) + (d2 + d3);                                       \
    float xh2 = (e0 + e1) + (e2 + e3);                                       \
    uint_t lo = cur[0], hi = cur[1];                                         \
    float g0v = f16b2f(lo & 0xffffu), g3v = f16b2f(lo >> 16);                \
    float g4v = f16b2f(hi & 0xffffu);                                        \
    float T1 = (float)((hi >> 16) & 255u) * (1.f / 255.f);                   \
    float T2 = (float)(hi >> 24) * (1.f / 255.f);                            \
    float i_t = sigm(g0v + xh0);                                             \
    float it1 = i_t * T1;                                                    \
    float cwa = tanh_s(g3v + xh1);                                           \
    float ctl = sigm((1.f - it1) * c_last + it1 * cwa);                      \
    float cnw = sigm((1.f - i_t) * c_last + i_t * T2 * cwa);                 \
    float o_t = sigm(g4v + xh2);                                             \
    float hn = o_t + tanh_s(ctl);                                            \
    h_lds[NXT][j] = (_Float16)hn;                                            \
    outp[(size_t)(t0 + (TT)) * 128] = hn;                                    \
    c_last = cnw; h_last = hn;                                               \
    asm volatile("s_waitcnt lgkmcnt(0)" ::: "memory");                       \
    __builtin_amdgcn_s_barrier();                                            \
  }

  for (int tt = 0; tt < TC; tt += 4) {
    SCAN_STEP(p0, tt, 0, 1);
    SCAN_STEP(p1, tt + 1, 1, 0);
    SCAN_STEP(p2, tt + 2, 0, 1);
    SCAN_STEP(p3, tt + 3, 1, 0);
  }
#undef SCAN_STEP

  if (t1 == 512) {
    out[(size_t)16777216 + b * 128 + j] = h_last;            // h_f
    out[(size_t)16777216 + 32768 + b * 128 + j] = c_last;    // c_f
  } else {
    sh[b * 128 + j] = h_last;
    sc[b * 128 + j] = c_last;
  }
}

// =====================================================================
extern "C" void kernel_launch(void* const* d_in, const int* in_sizes, int n_in,
                              void* d_out, int out_size, void* d_ws, size_t ws_size,
                              hipStream_t stream) {
  const float* x    = (const float*)d_in[0];
  const float* td   = (const float*)d_in[1];
  const float* wx   = (const float*)d_in[2];
  const float* wh   = (const float*)d_in[3];
  const float* wt   = (const float*)d_in[4];
  const float* bias = (const float*)d_in[5];
  float* out = (float*)d_out;

  // G: 256*TC rows * 128 cols * 8 B (TC=512 -> 134 MB; proven to fit ws)
  int TC = 512;
  while (TC > 16 && (size_t)256 * TC * 128 * 8 + 262144 > ws_size) TC >>= 1;
  int ltc = 0; while ((1 << ltc) < TC) ++ltc;

  u32x2* G = (u32x2*)d_ws;
  float* sh = (float*)((char*)d_ws + (size_t)256 * TC * 128 * 8);
  float* sc = sh + 256 * 128;

  const int rpt = 16;                         // 16-row tiles per gemm block
  const int gblocks = (256 * TC / 16) / rpt;

  for (int t0 = 0; t0 < 512; t0 += TC) {
    gemm_g<<<gblocks, 512, 0, stream>>>(x, td, wx, wt, bias, G, t0, TC, ltc, rpt);
    scan_k<<<256, 128, 0, stream>>>(G, wh, out, sh, sc, t0, t0 + TC, TC);
  }
}

// Round 11
// 438.315 us; speedup vs baseline: 1.3088x; 1.3088x over previous
//
#include <hip/hip_runtime.h>

typedef unsigned short ushort_t;
typedef unsigned int uint_t;
typedef short short8 __attribute__((ext_vector_type(8)));
typedef float f32x4 __attribute__((ext_vector_type(4)));
typedef float f32x2 __attribute__((ext_vector_type(2)));
typedef uint_t u32x2 __attribute__((ext_vector_type(2)));
typedef _Float16 half2_t __attribute__((ext_vector_type(2)));

__device__ __forceinline__ float sigm(float x) { return 1.f / (1.f + __expf(-x)); }
__device__ __forceinline__ float tanh_s(float x) {
  float e = __expf(2.f * fabsf(x));
  float r = 1.f - 2.f / (e + 1.f);
  return copysignf(r, x);
}
__device__ __forceinline__ float dot2h(half2_t a, half2_t b, float c) {
#if __has_builtin(__builtin_amdgcn_fdot2)
  return __builtin_amdgcn_fdot2(a, b, c, false);
#else
  return c + (float)a.x * (float)b.x + (float)a.y * (float)b.y;
#endif
}
__device__ __forceinline__ uint_t cvtpk_bf16(float a, float b) {
  uint_t r;
  asm("v_cvt_pk_bf16_f32 %0, %1, %2" : "=v"(r) : "v"(a), "v"(b));
  return r;
}
__device__ __forceinline__ short8 ld_cvt8(const float* p) {
  f32x4 v0 = *(const f32x4*)p;
  f32x4 v1 = *(const f32x4*)(p + 4);
  union { short8 s; uint_t u[4]; } r;
  r.u[0] = cvtpk_bf16(v0[0], v0[1]);
  r.u[1] = cvtpk_bf16(v0[2], v0[3]);
  r.u[2] = cvtpk_bf16(v1[0], v1[1]);
  r.u[3] = cvtpk_bf16(v1[2], v1[3]);
  return r.s;
}
__device__ __forceinline__ float f16b2f(uint_t bits) {
  union { ushort_t s; _Float16 h; } v; v.s = (ushort_t)bits; return (float)v.h;
}
__device__ __forceinline__ uint_t f2f16b(float f) {
  union { _Float16 h; ushort_t s; } v; v.h = (_Float16)f; return v.s;
}

#define MFMAB(a, b, c) __builtin_amdgcn_mfma_f32_16x16x32_bf16((a), (b), (c), 0, 0, 0)

// =====================================================================
// Kernel 1 (unchanged, measured ~65-70 us, PASS): fully-fused gate GEMM.
// G cell (8 bytes, u32x2): lo = {f16 g0+b0, f16 g3+b3}
//                          hi = {f16 g4+b4+gt2, u8 T1, u8 T2}
// =====================================================================
__global__ __launch_bounds__(512) void gemm_g(
    const float* __restrict__ x, const float* __restrict__ td,
    const float* __restrict__ wx, const float* __restrict__ wt,
    const float* __restrict__ bias, u32x2* __restrict__ G,
    int t0, int TC, int ltc, int rpt)
{
  const int tid = threadIdx.x;
  const int wv = tid >> 6, lane = tid & 63;
  const int l15 = lane & 15, lg = lane >> 4;
  const int jj = wv * 16 + l15;

  short8 Bx[5][2], Bt[3][2];
#pragma unroll
  for (int s = 0; s < 5; ++s)
#pragma unroll
    for (int f = 0; f < 2; ++f) {
      const float* wp = wx + (size_t)(f * 32 + lg * 8) * 640 + s * 128 + jj;
      union { short8 v; uint_t u[4]; } r;
#pragma unroll
      for (int q = 0; q < 4; ++q)
        r.u[q] = cvtpk_bf16(wp[(2 * q) * 640], wp[(2 * q + 1) * 640]);
      Bx[s][f] = r.v;
    }
#pragma unroll
  for (int s = 0; s < 3; ++s)
#pragma unroll
    for (int f = 0; f < 2; ++f) {
      const float* wp = wt + (size_t)(f * 32 + lg * 8) * 384 + s * 128 + jj;
      union { short8 v; uint_t u[4]; } r;
#pragma unroll
      for (int q = 0; q < 4; ++q) {
        float w0 = wp[(2 * q) * 384], w1 = wp[(2 * q + 1) * 384];
        if (s == 0) { w0 = fminf(w0, 0.f); w1 = fminf(w1, 0.f); }
        r.u[q] = cvtpk_bf16(w0, w1);
      }
      Bt[s][f] = r.v;
    }

  const float b0f = bias[jj], b1f = bias[128 + jj], b2f = bias[256 + jj];
  const float b3f = bias[384 + jj], b4f = bias[512 + jj];

#pragma unroll 1
  for (int it = 0; it < rpt; ++it) {
    const int m0 = (blockIdx.x * rpt + it) * 16;
    const int m = m0 + l15;
    const int bb = m >> ltc, tt = m & (TC - 1);
    const size_t ro = ((size_t)(bb * 512) + t0 + tt) * 64 + lg * 8;
    short8 xa0 = ld_cvt8(x + ro), xa1 = ld_cvt8(x + ro + 32);
    short8 ta0 = ld_cvt8(td + ro), ta1 = ld_cvt8(td + ro + 32);

    f32x4 g0{}, g1{}, g2{}, g3{}, g4{}, q0{}, q1{}, q2{};
    g0 = MFMAB(xa0, Bx[0][0], g0); g0 = MFMAB(xa1, Bx[0][1], g0);
    g1 = MFMAB(xa0, Bx[1][0], g1); g1 = MFMAB(xa1, Bx[1][1], g1);
    g2 = MFMAB(xa0, Bx[2][0], g2); g2 = MFMAB(xa1, Bx[2][1], g2);
    g3 = MFMAB(xa0, Bx[3][0], g3); g3 = MFMAB(xa1, Bx[3][1], g3);
    g4 = MFMAB(xa0, Bx[4][0], g4); g4 = MFMAB(xa1, Bx[4][1], g4);
    q0 = MFMAB(ta0, Bt[0][0], q0); q0 = MFMAB(ta1, Bt[0][1], q0);
    q1 = MFMAB(ta0, Bt[1][0], q1); q1 = MFMAB(ta1, Bt[1][1], q1);
    q2 = MFMAB(ta0, Bt[2][0], q2); q2 = MFMAB(ta1, Bt[2][1], q2);

#pragma unroll
    for (int r = 0; r < 4; ++r) {
      float v0 = g0[r] + b0f;
      float T1 = sigm(g1[r] + b1f + tanh_s(q0[r]));
      float T2 = sigm(g2[r] + b2f + tanh_s(q1[r]));
      float v3 = g3[r] + b3f;
      float v4 = g4[r] + b4f + q2[r];
      uint_t t1u = (uint_t)(T1 * 255.f + 0.5f);
      uint_t t2u = (uint_t)(T2 * 255.f + 0.5f);
      u32x2 P;
      P[0] = f2f16b(v0) | (f2f16b(v3) << 16);
      P[1] = f2f16b(v4) | (t1u << 16) | (t2u << 24);
      G[(size_t)(m0 + lg * 4 + r) * 128 + jj] = P;
    }
  }
}

// =====================================================================
// Kernel 2: serial scan, one-barrier one-LDS-trip structure.
// 1 block = 1 batch row, 256 threads (4 waves, 1/SIMD).
// Wave w owns cols w*32..+31; lane = split*32+off (split = k-half).
// Per step: 8 uniform ds_read_b128 (this split's 64 h, f16, dbuf LDS)
// -> 96 dot2 (12 chains) -> shfl_xor(32) x3 merges k-halves in-wave
// -> gates on ALL lanes (2x redundant, no divergence) -> split0 writes
// h' + out -> lgkmcnt(0) -> ONE s_barrier.  G prefetched depth-4.
// FIX vs round 10: h base offset is split*8 short8s (64 halves), was
// split*4 (split 1 read h[32..95] against W rows 64..127).
// =====================================================================
__global__ __launch_bounds__(256) void scan_k(
    const u32x2* __restrict__ G, const float* __restrict__ wh,
    float* __restrict__ out, float* __restrict__ sh, float* __restrict__ sc,
    int t0, int t1, int TC)
{
  __shared__ __attribute__((aligned(16))) _Float16 h2[2][128];
  const int tid = threadIdx.x;
  const int b = blockIdx.x;
  const int lane = tid & 63;
  const int w = tid >> 6;          // wave 0..3
  const int split = lane >> 5;     // k-half 0,1
  const int off = lane & 31;
  const int col = w * 32 + off;    // 0..127 (each col has 2 replicas)

  // Wh[split*64 + 2k..+1][seg*128 + col] as f16 pairs (96 VGPRs)
  half2_t w2[3][32];
#pragma unroll
  for (int s = 0; s < 3; ++s) {
    const float* wp = wh + (size_t)(split * 64) * 384 + s * 128 + col;
#pragma unroll
    for (int k = 0; k < 32; ++k)
      w2[s][k] = half2_t{(_Float16)wp[(size_t)(2 * k) * 384],
                         (_Float16)wp[(size_t)(2 * k + 1) * 384]};
  }

  float c_last = 0.f, h0v = 0.f;
  if (t0 > 0) { h0v = sh[b * 128 + col]; c_last = sc[b * 128 + col]; }
  float h_last = h0v;
  if (lane < 32) h2[0][col] = (_Float16)h0v;

  const u32x2* Gp = G + (size_t)b * TC * 128 + col;
  float* outp = out + (size_t)b * 65536 + col;

  u32x2 p0 = Gp[0], p1 = Gp[128], p2 = Gp[256], p3 = Gp[384];
  __syncthreads();

#define SCAN_STEP(P, TT, CUR, NXT)                                           \
  {                                                                          \
    u32x2 cur = P;                                                           \
    int tp = (TT) + 4; if (tp > TC - 1) tp = TC - 1;                         \
    P = Gp[(size_t)tp * 128];                                                \
    const short8* hv8 = ((const short8*)h2[CUR]) + split * 8;                \
    float a0=0.f,a1=0.f,a2=0.f,a3=0.f;                                       \
    float d0=0.f,d1=0.f,d2=0.f,d3=0.f;                                       \
    float e0=0.f,e1=0.f,e2=0.f,e3=0.f;                                       \
    _Pragma("unroll")                                                        \
    for (int kk = 0; kk < 8; ++kk) {                                         \
      union { short8 s; half2_t h[4]; } u; u.s = hv8[kk];                    \
      a0 = dot2h(u.h[0], w2[0][kk * 4 + 0], a0);                             \
      a1 = dot2h(u.h[1], w2[0][kk * 4 + 1], a1);                             \
      a2 = dot2h(u.h[2], w2[0][kk * 4 + 2], a2);                             \
      a3 = dot2h(u.h[3], w2[0][kk * 4 + 3], a3);                             \
      d0 = dot2h(u.h[0], w2[1][kk * 4 + 0], d0);                             \
      d1 = dot2h(u.h[1], w2[1][kk * 4 + 1], d1);                             \
      d2 = dot2h(u.h[2], w2[1][kk * 4 + 2], d2);                             \
      d3 = dot2h(u.h[3], w2[1][kk * 4 + 3], d3);                             \
      e0 = dot2h(u.h[0], w2[2][kk * 4 + 0], e0);                             \
      e1 = dot2h(u.h[1], w2[2][kk * 4 + 1], e1);                             \
      e2 = dot2h(u.h[2], w2[2][kk * 4 + 2], e2);                             \
      e3 = dot2h(u.h[3], w2[2][kk * 4 + 3], e3);                             \
    }                                                                        \
    float xh0 = (a0 + a1) + (a2 + a3); xh0 += __shfl_xor(xh0, 32);           \
    float xh1 = (d0 + d1) + (d2 + d3); xh1 += __shfl_xor(xh1, 32);           \
    float xh2 = (e0 + e1) + (e2 + e3); xh2 += __shfl_xor(xh2, 32);           \
    uint_t lo = cur[0], hi = cur[1];                                         \
    float g0v = f16b2f(lo & 0xffffu), g3v = f16b2f(lo >> 16);                \
    float g4v = f16b2f(hi & 0xffffu);                                        \
    float T1 = (float)((hi >> 16) & 255u) * (1.f / 255.f);                   \
    float T2 = (float)(hi >> 24) * (1.f / 255.f);                            \
    float i_t = sigm(g0v + xh0);                                             \
    float it1 = i_t * T1;                                                    \
    float cwa = tanh_s(g3v + xh1);                                           \
    float ctl = sigm((1.f - it1) * c_last + it1 * cwa);                      \
    float cnw = sigm((1.f - i_t) * c_last + i_t * T2 * cwa);                 \
    float o_t = sigm(g4v + xh2);                                             \
    float hn = o_t + tanh_s(ctl);                                            \
    if (lane < 32) {                                                         \
      h2[NXT][col] = (_Float16)hn;                                           \
      outp[(size_t)(t0 + (TT)) * 128] = hn;                                  \
    }                                                                        \
    c_last = cnw; h_last = hn;                                               \
    asm volatile("s_waitcnt lgkmcnt(0)" ::: "memory");                       \
    __builtin_amdgcn_s_barrier();                                            \
  }

  for (int tt = 0; tt < TC; tt += 4) {
    SCAN_STEP(p0, tt, 0, 1);
    SCAN_STEP(p1, tt + 1, 1, 0);
    SCAN_STEP(p2, tt + 2, 0, 1);
    SCAN_STEP(p3, tt + 3, 1, 0);
  }
#undef SCAN_STEP

  if (lane < 32) {
    if (t1 == 512) {
      out[(size_t)16777216 + b * 128 + col] = h_last;            // h_f
      out[(size_t)16777216 + 32768 + b * 128 + col] = c_last;    // c_f
    } else {
      sh[b * 128 + col] = h_last;
      sc[b * 128 + col] = c_last;
    }
  }
}

// =====================================================================
extern "C" void kernel_launch(void* const* d_in, const int* in_sizes, int n_in,
                              void* d_out, int out_size, void* d_ws, size_t ws_size,
                              hipStream_t stream) {
  const float* x    = (const float*)d_in[0];
  const float* td   = (const float*)d_in[1];
  const float* wx   = (const float*)d_in[2];
  const float* wh   = (const float*)d_in[3];
  const float* wt   = (const float*)d_in[4];
  const float* bias = (const float*)d_in[5];
  float* out = (float*)d_out;

  // G: 256*TC rows * 128 cols * 8 B (TC=512 -> 134 MB; proven to fit ws)
  int TC = 512;
  while (TC > 16 && (size_t)256 * TC * 128 * 8 + 262144 > ws_size) TC >>= 1;
  int ltc = 0; while ((1 << ltc) < TC) ++ltc;

  u32x2* G = (u32x2*)d_ws;
  float* sh = (float*)((char*)d_ws + (size_t)256 * TC * 128 * 8);
  float* sc = sh + 256 * 128;

  const int rpt = 16;                         // 16-row tiles per gemm block
  const int gblocks = (256 * TC / 16) / rpt;

  for (int t0 = 0; t0 < 512; t0 += TC) {
    gemm_g<<<gblocks, 512, 0, stream>>>(x, td, wx, wt, bias, G, t0, TC, ltc, rpt);
    scan_k<<<256, 256, 0, stream>>>(G, wh, out, sh, sc, t0, t0 + TC, TC);
  }
}

// Round 12
// 430.581 us; speedup vs baseline: 1.3323x; 1.0180x over previous
//
#include <hip/hip_runtime.h>

typedef unsigned short ushort_t;
typedef unsigned int uint_t;
typedef short short8 __attribute__((ext_vector_type(8)));
typedef float f32x4 __attribute__((ext_vector_type(4)));
typedef float f32x2 __attribute__((ext_vector_type(2)));
typedef uint_t u32x2 __attribute__((ext_vector_type(2)));
typedef _Float16 half2_t __attribute__((ext_vector_type(2)));

__device__ __forceinline__ float sigm(float x) { return 1.f / (1.f + __expf(-x)); }
__device__ __forceinline__ float tanh_s(float x) {
  float e = __expf(2.f * fabsf(x));
  float r = 1.f - 2.f / (e + 1.f);
  return copysignf(r, x);
}
__device__ __forceinline__ float dot2h(half2_t a, half2_t b, float c) {
#if __has_builtin(__builtin_amdgcn_fdot2)
  return __builtin_amdgcn_fdot2(a, b, c, false);
#else
  return c + (float)a.x * (float)b.x + (float)a.y * (float)b.y;
#endif
}
__device__ __forceinline__ uint_t cvtpk_bf16(float a, float b) {
  uint_t r;
  asm("v_cvt_pk_bf16_f32 %0, %1, %2" : "=v"(r) : "v"(a), "v"(b));
  return r;
}
__device__ __forceinline__ short8 ld_cvt8(const float* p) {
  f32x4 v0 = *(const f32x4*)p;
  f32x4 v1 = *(const f32x4*)(p + 4);
  union { short8 s; uint_t u[4]; } r;
  r.u[0] = cvtpk_bf16(v0[0], v0[1]);
  r.u[1] = cvtpk_bf16(v0[2], v0[3]);
  r.u[2] = cvtpk_bf16(v1[0], v1[1]);
  r.u[3] = cvtpk_bf16(v1[2], v1[3]);
  return r.s;
}
__device__ __forceinline__ float f16b2f(uint_t bits) {
  union { ushort_t s; _Float16 h; } v; v.s = (ushort_t)bits; return (float)v.h;
}
__device__ __forceinline__ uint_t f2f16b(float f) {
  union { _Float16 h; ushort_t s; } v; v.h = (_Float16)f; return v.s;
}

#define MFMAB(a, b, c) __builtin_amdgcn_mfma_f32_16x16x32_bf16((a), (b), (c), 0, 0, 0)

// =====================================================================
// Kernel 1 (unchanged, measured ~65-70 us, PASS): fully-fused gate GEMM.
// G cell (8 bytes, u32x2): lo = {f16 g0+b0, f16 g3+b3}
//                          hi = {f16 g4+b4+gt2, u8 T1, u8 T2}
// =====================================================================
__global__ __launch_bounds__(512) void gemm_g(
    const float* __restrict__ x, const float* __restrict__ td,
    const float* __restrict__ wx, const float* __restrict__ wt,
    const float* __restrict__ bias, u32x2* __restrict__ G,
    int t0, int TC, int ltc, int rpt)
{
  const int tid = threadIdx.x;
  const int wv = tid >> 6, lane = tid & 63;
  const int l15 = lane & 15, lg = lane >> 4;
  const int jj = wv * 16 + l15;

  short8 Bx[5][2], Bt[3][2];
#pragma unroll
  for (int s = 0; s < 5; ++s)
#pragma unroll
    for (int f = 0; f < 2; ++f) {
      const float* wp = wx + (size_t)(f * 32 + lg * 8) * 640 + s * 128 + jj;
      union { short8 v; uint_t u[4]; } r;
#pragma unroll
      for (int q = 0; q < 4; ++q)
        r.u[q] = cvtpk_bf16(wp[(2 * q) * 640], wp[(2 * q + 1) * 640]);
      Bx[s][f] = r.v;
    }
#pragma unroll
  for (int s = 0; s < 3; ++s)
#pragma unroll
    for (int f = 0; f < 2; ++f) {
      const float* wp = wt + (size_t)(f * 32 + lg * 8) * 384 + s * 128 + jj;
      union { short8 v; uint_t u[4]; } r;
#pragma unroll
      for (int q = 0; q < 4; ++q) {
        float w0 = wp[(2 * q) * 384], w1 = wp[(2 * q + 1) * 384];
        if (s == 0) { w0 = fminf(w0, 0.f); w1 = fminf(w1, 0.f); }
        r.u[q] = cvtpk_bf16(w0, w1);
      }
      Bt[s][f] = r.v;
    }

  const float b0f = bias[jj], b1f = bias[128 + jj], b2f = bias[256 + jj];
  const float b3f = bias[384 + jj], b4f = bias[512 + jj];

#pragma unroll 1
  for (int it = 0; it < rpt; ++it) {
    const int m0 = (blockIdx.x * rpt + it) * 16;
    const int m = m0 + l15;
    const int bb = m >> ltc, tt = m & (TC - 1);
    const size_t ro = ((size_t)(bb * 512) + t0 + tt) * 64 + lg * 8;
    short8 xa0 = ld_cvt8(x + ro), xa1 = ld_cvt8(x + ro + 32);
    short8 ta0 = ld_cvt8(td + ro), ta1 = ld_cvt8(td + ro + 32);

    f32x4 g0{}, g1{}, g2{}, g3{}, g4{}, q0{}, q1{}, q2{};
    g0 = MFMAB(xa0, Bx[0][0], g0); g0 = MFMAB(xa1, Bx[0][1], g0);
    g1 = MFMAB(xa0, Bx[1][0], g1); g1 = MFMAB(xa1, Bx[1][1], g1);
    g2 = MFMAB(xa0, Bx[2][0], g2); g2 = MFMAB(xa1, Bx[2][1], g2);
    g3 = MFMAB(xa0, Bx[3][0], g3); g3 = MFMAB(xa1, Bx[3][1], g3);
    g4 = MFMAB(xa0, Bx[4][0], g4); g4 = MFMAB(xa1, Bx[4][1], g4);
    q0 = MFMAB(ta0, Bt[0][0], q0); q0 = MFMAB(ta1, Bt[0][1], q0);
    q1 = MFMAB(ta0, Bt[1][0], q1); q1 = MFMAB(ta1, Bt[1][1], q1);
    q2 = MFMAB(ta0, Bt[2][0], q2); q2 = MFMAB(ta1, Bt[2][1], q2);

#pragma unroll
    for (int r = 0; r < 4; ++r) {
      float v0 = g0[r] + b0f;
      float T1 = sigm(g1[r] + b1f + tanh_s(q0[r]));
      float T2 = sigm(g2[r] + b2f + tanh_s(q1[r]));
      float v3 = g3[r] + b3f;
      float v4 = g4[r] + b4f + q2[r];
      uint_t t1u = (uint_t)(T1 * 255.f + 0.5f);
      uint_t t2u = (uint_t)(T2 * 255.f + 0.5f);
      u32x2 P;
      P[0] = f2f16b(v0) | (f2f16b(v3) << 16);
      P[1] = f2f16b(v4) | (t1u << 16) | (t2u << 24);
      G[(size_t)(m0 + lg * 4 + r) * 128 + jj] = P;
    }
  }
}

// =====================================================================
// Kernel 2: serial scan, one-barrier structure (R11) + BATCHED out
// stores.  1 block = 1 batch row, 256 threads (4 waves, 1/SIMD).
// Wave w owns cols w*32..+31; lane = split*32+off (split = k-half).
// Per step: 8 uniform ds_read_b128 -> 96 dot2 -> shfl_xor(32) merge ->
// gates (all lanes, 2x redundant) -> h' to dbuf LDS -> lgkm -> barrier.
// h' ALSO kept in named registers; every 8 steps one 8-store burst so
// stores never sit between a G-load and its vmcnt wait (in-order FIFO).
// G prefetch depth-8 in registers (p0..p7).
// =====================================================================
__global__ __launch_bounds__(256) void scan_k(
    const u32x2* __restrict__ G, const float* __restrict__ wh,
    float* __restrict__ out, float* __restrict__ sh, float* __restrict__ sc,
    int t0, int t1, int TC)
{
  __shared__ __attribute__((aligned(16))) _Float16 h2[2][128];
  const int tid = threadIdx.x;
  const int b = blockIdx.x;
  const int lane = tid & 63;
  const int w = tid >> 6;          // wave 0..3
  const int split = lane >> 5;     // k-half 0,1
  const int off = lane & 31;
  const int col = w * 32 + off;    // 0..127 (each col has 2 replicas)

  // Wh[split*64 + 2k..+1][seg*128 + col] as f16 pairs (96 VGPRs)
  half2_t w2[3][32];
#pragma unroll
  for (int s = 0; s < 3; ++s) {
    const float* wp = wh + (size_t)(split * 64) * 384 + s * 128 + col;
#pragma unroll
    for (int k = 0; k < 32; ++k)
      w2[s][k] = half2_t{(_Float16)wp[(size_t)(2 * k) * 384],
                         (_Float16)wp[(size_t)(2 * k + 1) * 384]};
  }

  float c_last = 0.f, h0v = 0.f;
  if (t0 > 0) { h0v = sh[b * 128 + col]; c_last = sc[b * 128 + col]; }
  float h_last = h0v;
  if (lane < 32) h2[0][col] = (_Float16)h0v;

  const u32x2* Gp = G + (size_t)b * TC * 128 + col;
  float* outp = out + (size_t)b * 65536 + col;

  u32x2 p0 = Gp[0],       p1 = Gp[128],     p2 = Gp[256],     p3 = Gp[384];
  u32x2 p4 = Gp[4 * 128], p5 = Gp[5 * 128], p6 = Gp[6 * 128], p7 = Gp[7 * 128];
  float hb0, hb1, hb2, hb3, hb4, hb5, hb6, hb7;
  __syncthreads();

#define SCAN_STEP(P, TT, CUR, NXT, HB)                                       \
  {                                                                          \
    u32x2 cur = P;                                                           \
    int tp = (TT) + 8; if (tp > TC - 1) tp = TC - 1;                         \
    P = Gp[(size_t)tp * 128];                                                \
    const short8* hv8 = ((const short8*)h2[CUR]) + split * 8;                \
    float a0=0.f,a1=0.f,a2=0.f,a3=0.f;                                       \
    float d0=0.f,d1=0.f,d2=0.f,d3=0.f;                                       \
    float e0=0.f,e1=0.f,e2=0.f,e3=0.f;                                       \
    _Pragma("unroll")                                                        \
    for (int kk = 0; kk < 8; ++kk) {                                         \
      union { short8 s; half2_t h[4]; } u; u.s = hv8[kk];                    \
      a0 = dot2h(u.h[0], w2[0][kk * 4 + 0], a0);                             \
      a1 = dot2h(u.h[1], w2[0][kk * 4 + 1], a1);                             \
      a2 = dot2h(u.h[2], w2[0][kk * 4 + 2], a2);                             \
      a3 = dot2h(u.h[3], w2[0][kk * 4 + 3], a3);                             \
      d0 = dot2h(u.h[0], w2[1][kk * 4 + 0], d0);                             \
      d1 = dot2h(u.h[1], w2[1][kk * 4 + 1], d1);                             \
      d2 = dot2h(u.h[2], w2[1][kk * 4 + 2], d2);                             \
      d3 = dot2h(u.h[3], w2[1][kk * 4 + 3], d3);                             \
      e0 = dot2h(u.h[0], w2[2][kk * 4 + 0], e0);                             \
      e1 = dot2h(u.h[1], w2[2][kk * 4 + 1], e1);                             \
      e2 = dot2h(u.h[2], w2[2][kk * 4 + 2], e2);                             \
      e3 = dot2h(u.h[3], w2[2][kk * 4 + 3], e3);                             \
    }                                                                        \
    float xh0 = (a0 + a1) + (a2 + a3); xh0 += __shfl_xor(xh0, 32);           \
    float xh1 = (d0 + d1) + (d2 + d3); xh1 += __shfl_xor(xh1, 32);           \
    float xh2 = (e0 + e1) + (e2 + e3); xh2 += __shfl_xor(xh2, 32);           \
    uint_t lo = cur[0], hi = cur[1];                                         \
    float g0v = f16b2f(lo & 0xffffu), g3v = f16b2f(lo >> 16);                \
    float g4v = f16b2f(hi & 0xffffu);                                        \
    float T1 = (float)((hi >> 16) & 255u) * (1.f / 255.f);                   \
    float T2 = (float)(hi >> 24) * (1.f / 255.f);                            \
    float i_t = sigm(g0v + xh0);                                             \
    float it1 = i_t * T1;                                                    \
    float cwa = tanh_s(g3v + xh1);                                           \
    float ctl = sigm((1.f - it1) * c_last + it1 * cwa);                      \
    float cnw = sigm((1.f - i_t) * c_last + i_t * T2 * cwa);                 \
    float o_t = sigm(g4v + xh2);                                             \
    float hn = o_t + tanh_s(ctl);                                            \
    HB = hn;                                                                 \
    if (lane < 32) h2[NXT][col] = (_Float16)hn;                              \
    c_last = cnw; h_last = hn;                                               \
    asm volatile("s_waitcnt lgkmcnt(0)" ::: "memory");                       \
    __builtin_amdgcn_s_barrier();                                            \
  }

  for (int tt = 0; tt < TC; tt += 8) {
    SCAN_STEP(p0, tt + 0, 0, 1, hb0);
    SCAN_STEP(p1, tt + 1, 1, 0, hb1);
    SCAN_STEP(p2, tt + 2, 0, 1, hb2);
    SCAN_STEP(p3, tt + 3, 1, 0, hb3);
    SCAN_STEP(p4, tt + 4, 0, 1, hb4);
    SCAN_STEP(p5, tt + 5, 1, 0, hb5);
    SCAN_STEP(p6, tt + 6, 0, 1, hb6);
    SCAN_STEP(p7, tt + 7, 1, 0, hb7);
    if (lane < 32) {
      float* op = outp + (size_t)(t0 + tt) * 128;
      op[0]       = hb0;
      op[128]     = hb1;
      op[2 * 128] = hb2;
      op[3 * 128] = hb3;
      op[4 * 128] = hb4;
      op[5 * 128] = hb5;
      op[6 * 128] = hb6;
      op[7 * 128] = hb7;
    }
  }
#undef SCAN_STEP

  if (lane < 32) {
    if (t1 == 512) {
      out[(size_t)16777216 + b * 128 + col] = h_last;            // h_f
      out[(size_t)16777216 + 32768 + b * 128 + col] = c_last;    // c_f
    } else {
      sh[b * 128 + col] = h_last;
      sc[b * 128 + col] = c_last;
    }
  }
}

// =====================================================================
extern "C" void kernel_launch(void* const* d_in, const int* in_sizes, int n_in,
                              void* d_out, int out_size, void* d_ws, size_t ws_size,
                              hipStream_t stream) {
  const float* x    = (const float*)d_in[0];
  const float* td   = (const float*)d_in[1];
  const float* wx   = (const float*)d_in[2];
  const float* wh   = (const float*)d_in[3];
  const float* wt   = (const float*)d_in[4];
  const float* bias = (const float*)d_in[5];
  float* out = (float*)d_out;

  // G: 256*TC rows * 128 cols * 8 B (TC=512 -> 134 MB; proven to fit ws)
  int TC = 512;
  while (TC > 16 && (size_t)256 * TC * 128 * 8 + 262144 > ws_size) TC >>= 1;
  int ltc = 0; while ((1 << ltc) < TC) ++ltc;

  u32x2* G = (u32x2*)d_ws;
  float* sh = (float*)((char*)d_ws + (size_t)256 * TC * 128 * 8);
  float* sc = sh + 256 * 128;

  const int rpt = 16;                         // 16-row tiles per gemm block
  const int gblocks = (256 * TC / 16) / rpt;

  for (int t0 = 0; t0 < 512; t0 += TC) {
    gemm_g<<<gblocks, 512, 0, stream>>>(x, td, wx, wt, bias, G, t0, TC, ltc, rpt);
    scan_k<<<256, 256, 0, stream>>>(G, wh, out, sh, sc, t0, t0 + TC, TC);
  }
}

// Round 14
// 425.597 us; speedup vs baseline: 1.3479x; 1.0117x over previous
//
#include <hip/hip_runtime.h>

typedef unsigned short ushort_t;
typedef unsigned int uint_t;
typedef short short8 __attribute__((ext_vector_type(8)));
typedef float f32x4 __attribute__((ext_vector_type(4)));
typedef float f32x2 __attribute__((ext_vector_type(2)));
typedef uint_t u32x2 __attribute__((ext_vector_type(2)));
typedef _Float16 half2_t __attribute__((ext_vector_type(2)));

__device__ __forceinline__ float sigm(float x) { return 1.f / (1.f + __expf(-x)); }
__device__ __forceinline__ float tanh_s(float x) {
  float e = __expf(2.f * fabsf(x));
  float r = 1.f - 2.f / (e + 1.f);
  return copysignf(r, x);
}
__device__ __forceinline__ float dot2h(half2_t a, half2_t b, float c) {
#if __has_builtin(__builtin_amdgcn_fdot2)
  return __builtin_amdgcn_fdot2(a, b, c, false);
#else
  return c + (float)a.x * (float)b.x + (float)a.y * (float)b.y;
#endif
}
__device__ __forceinline__ uint_t cvtpk_bf16(float a, float b) {
  uint_t r;
  asm("v_cvt_pk_bf16_f32 %0, %1, %2" : "=v"(r) : "v"(a), "v"(b));
  return r;
}
__device__ __forceinline__ short8 ld_cvt8(const float* p) {
  f32x4 v0 = *(const f32x4*)p;
  f32x4 v1 = *(const f32x4*)(p + 4);
  union { short8 s; uint_t u[4]; } r;
  r.u[0] = cvtpk_bf16(v0[0], v0[1]);
  r.u[1] = cvtpk_bf16(v0[2], v0[3]);
  r.u[2] = cvtpk_bf16(v1[0], v1[1]);
  r.u[3] = cvtpk_bf16(v1[2], v1[3]);
  return r.s;
}
__device__ __forceinline__ float f16b2f(uint_t bits) {
  union { ushort_t s; _Float16 h; } v; v.s = (ushort_t)bits; return (float)v.h;
}
__device__ __forceinline__ uint_t f2f16b(float f) {
  union { _Float16 h; ushort_t s; } v; v.h = (_Float16)f; return v.s;
}

#define MFMAB(a, b, c) __builtin_amdgcn_mfma_f32_16x16x32_bf16((a), (b), (c), 0, 0, 0)

// =====================================================================
// Kernel 1 (unchanged, measured ~65 us, PASS): fully-fused gate GEMM.
// G cell (8 bytes, u32x2): lo = {f16 g0+b0, f16 g3+b3}
//                          hi = {f16 g4+b4+gt2, u8 T1, u8 T2}
// =====================================================================
__global__ __launch_bounds__(512) void gemm_g(
    const float* __restrict__ x, const float* __restrict__ td,
    const float* __restrict__ wx, const float* __restrict__ wt,
    const float* __restrict__ bias, u32x2* __restrict__ G,
    int t0, int TC, int ltc, int rpt)
{
  const int tid = threadIdx.x;
  const int wv = tid >> 6, lane = tid & 63;
  const int l15 = lane & 15, lg = lane >> 4;
  const int jj = wv * 16 + l15;

  short8 Bx[5][2], Bt[3][2];
#pragma unroll
  for (int s = 0; s < 5; ++s)
#pragma unroll
    for (int f = 0; f < 2; ++f) {
      const float* wp = wx + (size_t)(f * 32 + lg * 8) * 640 + s * 128 + jj;
      union { short8 v; uint_t u[4]; } r;
#pragma unroll
      for (int q = 0; q < 4; ++q)
        r.u[q] = cvtpk_bf16(wp[(2 * q) * 640], wp[(2 * q + 1) * 640]);
      Bx[s][f] = r.v;
    }
#pragma unroll
  for (int s = 0; s < 3; ++s)
#pragma unroll
    for (int f = 0; f < 2; ++f) {
      const float* wp = wt + (size_t)(f * 32 + lg * 8) * 384 + s * 128 + jj;
      union { short8 v; uint_t u[4]; } r;
#pragma unroll
      for (int q = 0; q < 4; ++q) {
        float w0 = wp[(2 * q) * 384], w1 = wp[(2 * q + 1) * 384];
        if (s == 0) { w0 = fminf(w0, 0.f); w1 = fminf(w1, 0.f); }
        r.u[q] = cvtpk_bf16(w0, w1);
      }
      Bt[s][f] = r.v;
    }

  const float b0f = bias[jj], b1f = bias[128 + jj], b2f = bias[256 + jj];
  const float b3f = bias[384 + jj], b4f = bias[512 + jj];

#pragma unroll 1
  for (int it = 0; it < rpt; ++it) {
    const int m0 = (blockIdx.x * rpt + it) * 16;
    const int m = m0 + l15;
    const int bb = m >> ltc, tt = m & (TC - 1);
    const size_t ro = ((size_t)(bb * 512) + t0 + tt) * 64 + lg * 8;
    short8 xa0 = ld_cvt8(x + ro), xa1 = ld_cvt8(x + ro + 32);
    short8 ta0 = ld_cvt8(td + ro), ta1 = ld_cvt8(td + ro + 32);

    f32x4 g0{}, g1{}, g2{}, g3{}, g4{}, q0{}, q1{}, q2{};
    g0 = MFMAB(xa0, Bx[0][0], g0); g0 = MFMAB(xa1, Bx[0][1], g0);
    g1 = MFMAB(xa0, Bx[1][0], g1); g1 = MFMAB(xa1, Bx[1][1], g1);
    g2 = MFMAB(xa0, Bx[2][0], g2); g2 = MFMAB(xa1, Bx[2][1], g2);
    g3 = MFMAB(xa0, Bx[3][0], g3); g3 = MFMAB(xa1, Bx[3][1], g3);
    g4 = MFMAB(xa0, Bx[4][0], g4); g4 = MFMAB(xa1, Bx[4][1], g4);
    q0 = MFMAB(ta0, Bt[0][0], q0); q0 = MFMAB(ta1, Bt[0][1], q0);
    q1 = MFMAB(ta0, Bt[1][0], q1); q1 = MFMAB(ta1, Bt[1][1], q1);
    q2 = MFMAB(ta0, Bt[2][0], q2); q2 = MFMAB(ta1, Bt[2][1], q2);

#pragma unroll
    for (int r = 0; r < 4; ++r) {
      float v0 = g0[r] + b0f;
      float T1 = sigm(g1[r] + b1f + tanh_s(q0[r]));
      float T2 = sigm(g2[r] + b2f + tanh_s(q1[r]));
      float v3 = g3[r] + b3f;
      float v4 = g4[r] + b4f + q2[r];
      uint_t t1u = (uint_t)(T1 * 255.f + 0.5f);
      uint_t t2u = (uint_t)(T2 * 255.f + 0.5f);
      u32x2 P;
      P[0] = f2f16b(v0) | (f2f16b(v3) << 16);
      P[1] = f2f16b(v4) | (t1u << 16) | (t2u << 24);
      G[(size_t)(m0 + lg * 4 + r) * 128 + jj] = P;
    }
  }
}

// =====================================================================
// Kernel 2: serial scan (R12 structure) + G-decode hoisted to step top.
// k-half merge back to shfl_xor(32) (R12-proven; permlane32_swap builtin
// semantics did not match — R13 FAIL).  1 block = 1 batch row, 256
// threads (4 waves).  One barrier per step.  G prefetch depth-8; out
// stores batched every 8 steps.
// =====================================================================
__global__ __launch_bounds__(256) void scan_k(
    const u32x2* __restrict__ G, const float* __restrict__ wh,
    float* __restrict__ out, float* __restrict__ sh, float* __restrict__ sc,
    int t0, int t1, int TC)
{
  __shared__ __attribute__((aligned(16))) _Float16 h2[2][128];
  const int tid = threadIdx.x;
  const int b = blockIdx.x;
  const int lane = tid & 63;
  const int w = tid >> 6;          // wave 0..3
  const int split = lane >> 5;     // k-half 0,1
  const int off = lane & 31;
  const int col = w * 32 + off;    // 0..127 (each col has 2 replicas)

  // Wh[split*64 + 2k..+1][seg*128 + col] as f16 pairs (96 VGPRs)
  half2_t w2[3][32];
#pragma unroll
  for (int s = 0; s < 3; ++s) {
    const float* wp = wh + (size_t)(split * 64) * 384 + s * 128 + col;
#pragma unroll
    for (int k = 0; k < 32; ++k)
      w2[s][k] = half2_t{(_Float16)wp[(size_t)(2 * k) * 384],
                         (_Float16)wp[(size_t)(2 * k + 1) * 384]};
  }

  float c_last = 0.f, h0v = 0.f;
  if (t0 > 0) { h0v = sh[b * 128 + col]; c_last = sc[b * 128 + col]; }
  float h_last = h0v;
  if (lane < 32) h2[0][col] = (_Float16)h0v;

  const u32x2* Gp = G + (size_t)b * TC * 128 + col;
  float* outp = out + (size_t)b * 65536 + col;

  u32x2 p0 = Gp[0],       p1 = Gp[128],     p2 = Gp[256],     p3 = Gp[384];
  u32x2 p4 = Gp[4 * 128], p5 = Gp[5 * 128], p6 = Gp[6 * 128], p7 = Gp[7 * 128];
  float hb0, hb1, hb2, hb3, hb4, hb5, hb6, hb7;
  __syncthreads();

#define SCAN_STEP(P, TT, CUR, NXT, HB)                                       \
  {                                                                          \
    /* step-top: rotate prefetch and decode G cell immediately (indep) */    \
    uint_t lo = P[0], hi = P[1];                                             \
    int tp = (TT) + 8; if (tp > TC - 1) tp = TC - 1;                         \
    P = Gp[(size_t)tp * 128];                                                \
    float g0v = f16b2f(lo & 0xffffu), g3v = f16b2f(lo >> 16);                \
    float g4v = f16b2f(hi & 0xffffu);                                        \
    float T1 = (float)((hi >> 16) & 255u) * (1.f / 255.f);                   \
    float T2 = (float)(hi >> 24) * (1.f / 255.f);                            \
    const short8* hv8 = ((const short8*)h2[CUR]) + split * 8;                \
    float a0=0.f,a1=0.f,a2=0.f,a3=0.f;                                       \
    float d0=0.f,d1=0.f,d2=0.f,d3=0.f;                                       \
    float e0=0.f,e1=0.f,e2=0.f,e3=0.f;                                       \
    _Pragma("unroll")                                                        \
    for (int kk = 0; kk < 8; ++kk) {                                         \
      union { short8 s; half2_t h[4]; } u; u.s = hv8[kk];                    \
      a0 = dot2h(u.h[0], w2[0][kk * 4 + 0], a0);                             \
      a1 = dot2h(u.h[1], w2[0][kk * 4 + 1], a1);                             \
      a2 = dot2h(u.h[2], w2[0][kk * 4 + 2], a2);                             \
      a3 = dot2h(u.h[3], w2[0][kk * 4 + 3], a3);                             \
      d0 = dot2h(u.h[0], w2[1][kk * 4 + 0], d0);                             \
      d1 = dot2h(u.h[1], w2[1][kk * 4 + 1], d1);                             \
      d2 = dot2h(u.h[2], w2[1][kk * 4 + 2], d2);                             \
      d3 = dot2h(u.h[3], w2[1][kk * 4 + 3], d3);                             \
      e0 = dot2h(u.h[0], w2[2][kk * 4 + 0], e0);                             \
      e1 = dot2h(u.h[1], w2[2][kk * 4 + 1], e1);                             \
      e2 = dot2h(u.h[2], w2[2][kk * 4 + 2], e2);                             \
      e3 = dot2h(u.h[3], w2[2][kk * 4 + 3], e3);                             \
    }                                                                        \
    float xh0 = (a0 + a1) + (a2 + a3); xh0 += __shfl_xor(xh0, 32);           \
    float xh1 = (d0 + d1) + (d2 + d3); xh1 += __shfl_xor(xh1, 32);           \
    float xh2 = (e0 + e1) + (e2 + e3); xh2 += __shfl_xor(xh2, 32);           \
    float i_t = sigm(g0v + xh0);                                             \
    float it1 = i_t * T1;                                                    \
    float cwa = tanh_s(g3v + xh1);                                           \
    float ctl = sigm((1.f - it1) * c_last + it1 * cwa);                      \
    float cnw = sigm((1.f - i_t) * c_last + i_t * T2 * cwa);                 \
    float o_t = sigm(g4v + xh2);                                             \
    float hn = o_t + tanh_s(ctl);                                            \
    HB = hn;                                                                 \
    if (lane < 32) h2[NXT][col] = (_Float16)hn;                              \
    c_last = cnw; h_last = hn;                                               \
    asm volatile("s_waitcnt lgkmcnt(0)" ::: "memory");                       \
    __builtin_amdgcn_s_barrier();                                            \
  }

  for (int tt = 0; tt < TC; tt += 8) {
    SCAN_STEP(p0, tt + 0, 0, 1, hb0);
    SCAN_STEP(p1, tt + 1, 1, 0, hb1);
    SCAN_STEP(p2, tt + 2, 0, 1, hb2);
    SCAN_STEP(p3, tt + 3, 1, 0, hb3);
    SCAN_STEP(p4, tt + 4, 0, 1, hb4);
    SCAN_STEP(p5, tt + 5, 1, 0, hb5);
    SCAN_STEP(p6, tt + 6, 0, 1, hb6);
    SCAN_STEP(p7, tt + 7, 1, 0, hb7);
    if (lane < 32) {
      float* op = outp + (size_t)(t0 + tt) * 128;
      op[0]       = hb0;
      op[128]     = hb1;
      op[2 * 128] = hb2;
      op[3 * 128] = hb3;
      op[4 * 128] = hb4;
      op[5 * 128] = hb5;
      op[6 * 128] = hb6;
      op[7 * 128] = hb7;
    }
  }
#undef SCAN_STEP

  if (lane < 32) {
    if (t1 == 512) {
      out[(size_t)16777216 + b * 128 + col] = h_last;            // h_f
      out[(size_t)16777216 + 32768 + b * 128 + col] = c_last;    // c_f
    } else {
      sh[b * 128 + col] = h_last;
      sc[b * 128 + col] = c_last;
    }
  }
}

// =====================================================================
extern "C" void kernel_launch(void* const* d_in, const int* in_sizes, int n_in,
                              void* d_out, int out_size, void* d_ws, size_t ws_size,
                              hipStream_t stream) {
  const float* x    = (const float*)d_in[0];
  const float* td   = (const float*)d_in[1];
  const float* wx   = (const float*)d_in[2];
  const float* wh   = (const float*)d_in[3];
  const float* wt   = (const float*)d_in[4];
  const float* bias = (const float*)d_in[5];
  float* out = (float*)d_out;

  // G: 256*TC rows * 128 cols * 8 B (TC=512 -> 134 MB; proven to fit ws)
  int TC = 512;
  while (TC > 16 && (size_t)256 * TC * 128 * 8 + 262144 > ws_size) TC >>= 1;
  int ltc = 0; while ((1 << ltc) < TC) ++ltc;

  u32x2* G = (u32x2*)d_ws;
  float* sh = (float*)((char*)d_ws + (size_t)256 * TC * 128 * 8);
  float* sc = sh + 256 * 128;

  const int rpt = 16;                         // 16-row tiles per gemm block
  const int gblocks = (256 * TC / 16) / rpt;

  for (int t0 = 0; t0 < 512; t0 += TC) {
    gemm_g<<<gblocks, 512, 0, stream>>>(x, td, wx, wt, bias, G, t0, TC, ltc, rpt);
    scan_k<<<256, 256, 0, stream>>>(G, wh, out, sh, sc, t0, t0 + TC, TC);
  }
}